// Round 3
// baseline (154.703 us; speedup 1.0000x reference)
//
#include <hip/hip_runtime.h>

#define NN 8
#define MM 8
#define NH1 64
#define NH2 32

__global__ __launch_bounds__(256, 4) void barrier_policy_kernel(
    const float* __restrict__ x_g,
    const float* __restrict__ W1,  const float* __restrict__ b1,
    const float* __restrict__ W21, const float* __restrict__ b21,
    const float* __restrict__ W22, const float* __restrict__ b22,
    const float* __restrict__ W31, const float* __restrict__ b31,
    const float* __restrict__ W32, const float* __restrict__ b32,
    const float* __restrict__ Amat, const float* __restrict__ Gmat,
    const float* __restrict__ mean, const float* __restrict__ std_,
    float* __restrict__ out, int B)
{
    const int row = blockIdx.x * blockDim.x + threadIdx.x;
    if (row >= B) return;

    // ---- load x (vectorized, 32B/thread) ----
    float x[NN];
    {
        const float4* xv = reinterpret_cast<const float4*>(x_g + (size_t)row * NN);
        float4 a0 = xv[0], a1 = xv[1];
        x[0] = a0.x; x[1] = a0.y; x[2] = a0.z; x[3] = a0.w;
        x[4] = a1.x; x[5] = a1.y; x[6] = a1.z; x[7] = a1.w;
    }

    // ---- un-normalized state ----
    float x0[NN];
#pragma unroll
    for (int i = 0; i < NN; ++i) x0[i] = fmaf(x[i], std_[i], mean[i]);

    // ---- layer 1 fused into layer 2: for each k, h1[k] = relu(x@W1_col_k+b1),
    //      immediately accumulated into x21/x22 (keeps live regs = 64, not 128)
    float x21[NH2], x22[NH2];
#pragma unroll
    for (int j = 0; j < NH2; ++j) { x21[j] = b21[j]; x22[j] = b22[j]; }
#pragma unroll
    for (int k = 0; k < NH1; ++k) {
        float acc = b1[k];
#pragma unroll
        for (int i = 0; i < NN; ++i) acc = fmaf(x[i], W1[i * NH1 + k], acc);
        const float h = fmaxf(acc, 0.0f);
#pragma unroll
        for (int j = 0; j < NH2; ++j) {
            x21[j] = fmaf(h, W21[k * NH2 + j], x21[j]);
            x22[j] = fmaf(h, W22[k * NH2 + j], x22[j]);
        }
    }
#pragma unroll
    for (int j = 0; j < NH2; ++j) {
        x21[j] = fmaxf(x21[j], 0.0f);
        x22[j] = fmaxf(x22[j], 0.0f);
    }

    // ---- heads: px = x21@W31+b31 ; alphax = 4*sigmoid(x22@W32+b32) ----
    float p[MM];
#pragma unroll
    for (int j = 0; j < MM; ++j) {
        float acc = b31[j];
#pragma unroll
        for (int k = 0; k < NH2; ++k) acc = fmaf(x21[k], W31[k * MM + j], acc);
        p[j] = acc;
    }
    float s = b32[0];
#pragma unroll
    for (int k = 0; k < NH2; ++k) s = fmaf(x22[k], W32[k], s);
    const float alphax = 4.0f / (1.0f + __expf(-s));

    // ---- barrier terms ----
    float hx = 16.0f;
#pragma unroll
    for (int i = 0; i < NN; ++i) hx = fmaf(-x0[i], x0[i], hx);

    float dh[NN];
#pragma unroll
    for (int i = 0; i < NN; ++i) dh[i] = -2.0f * x0[i];

    float Lfhx = 0.0f;
#pragma unroll
    for (int i = 0; i < NN; ++i) {
        float fx = 0.0f;
#pragma unroll
        for (int k = 0; k < NN; ++k) fx = fmaf(Amat[i * NN + k], x0[k], fx);
        Lfhx = fmaf(dh[i], fx, Lfhx);
    }

    float g[MM];
#pragma unroll
    for (int j = 0; j < MM; ++j) {
        float acc = 0.0f;
#pragma unroll
        for (int i = 0; i < NN; ++i) acc = fmaf(dh[i], Gmat[i * MM + j], acc);
        g[j] = acc;
    }

    const float c0 = fmaf(alphax, hx, Lfhx);

    // ---- QP via exact piecewise-linear root isolation --------------------
    // c(lam) = c0 + sum_j g_j * clip(-p_j + lam*g_j, -1, 1): nondecreasing,
    // piecewise-linear with <=16 breakpoints (p_j -/+ 1)/g_j. Evaluate c at
    // every positive breakpoint (independent -> full ILP), take the segment
    // [lamL, lamR] bracketing the root, classify the active set strictly
    // inside it, then the reference's closed-form KKT refinement is exact.
#define C_OF(lam, cres)                                              \
    do {                                                             \
        float c_ = c0;                                               \
        _Pragma("unroll")                                            \
        for (int j_ = 0; j_ < MM; ++j_) {                            \
            float u_ = fmaf((lam), g[j_], -p[j_]);                   \
            u_ = fminf(fmaxf(u_, -1.0f), 1.0f);                      \
            c_ = fmaf(g[j_], u_, c_);                                \
        }                                                            \
        (cres) = c_;                                                 \
    } while (0)

    float c_zero;
    C_OF(0.0f, c_zero);
    const bool viol = (c_zero < 0.0f);

    const float BIGR = 3.0e38f;            // sentinel: no right bracket found
    float lamL = 0.0f, lamR = BIGR;
#pragma unroll
    for (int j = 0; j < MM; ++j) {
        const float gj = g[j];
        const bool gz = (gj != 0.0f);
        const float bpa = gz ? (p[j] - 1.0f) / gj : -1.0f;
        const float bpb = gz ? (p[j] + 1.0f) / gj : -1.0f;
        float ca, cb;
        C_OF(bpa, ca);
        C_OF(bpb, cb);
        lamL = (bpa > 0.0f && ca <  0.0f && bpa > lamL) ? bpa : lamL;
        lamR = (bpa > 0.0f && ca >= 0.0f && bpa < lamR) ? bpa : lamR;
        lamL = (bpb > 0.0f && cb <  0.0f && bpb > lamL) ? bpb : lamL;
        lamR = (bpb > 0.0f && cb >= 0.0f && bpb < lamR) ? bpb : lamR;
    }

    // lam_test sits strictly inside the root's segment (same segment the
    // reference's bisected lam_b lands in). Infeasible (c(inf)<0): the
    // reference's bracket caps at 2^40 -> classify there. !viol: lam=0.
    const bool infeas = (lamR == BIGR);
    float lam_t = infeas ? 1.099511627776e12f : 0.5f * (lamL + lamR);
    lam_t = viol ? lam_t : 0.0f;

    // frozen active set -> closed-form lambda (exact KKT refinement, == ref)
    float denom = 0.0f, num = c0;
    bool lowb[MM], highb[MM];
#pragma unroll
    for (int j = 0; j < MM; ++j) {
        const float uraw = fmaf(lam_t, g[j], -p[j]);
        lowb[j]  = (uraw <= -1.0f);
        highb[j] = (uraw >= 1.0f);
        const bool freeb = !(lowb[j] || highb[j]);
        denom += freeb ? g[j] * g[j] : 0.0f;
        num   += lowb[j] ? -g[j] : (highb[j] ? g[j] : -g[j] * p[j]);
    }
    const float lam = viol ? (-num / (denom + 1e-12f)) : 0.0f;

    float uo[MM];
#pragma unroll
    for (int j = 0; j < MM; ++j) {
        const float uf = fmaf(lam, g[j], -p[j]);
        uo[j] = lowb[j] ? -1.0f : (highb[j] ? 1.0f : uf);
    }

    // ---- store (vectorized) ----
    float4* ov = reinterpret_cast<float4*>(out + (size_t)row * MM);
    ov[0] = make_float4(uo[0], uo[1], uo[2], uo[3]);
    ov[1] = make_float4(uo[4], uo[5], uo[6], uo[7]);
#undef C_OF
}

extern "C" void kernel_launch(void* const* d_in, const int* in_sizes, int n_in,
                              void* d_out, int out_size, void* d_ws, size_t ws_size,
                              hipStream_t stream) {
    const float* x    = (const float*)d_in[0];
    const float* W1   = (const float*)d_in[1];
    const float* b1   = (const float*)d_in[2];
    const float* W21  = (const float*)d_in[3];
    const float* b21  = (const float*)d_in[4];
    const float* W22  = (const float*)d_in[5];
    const float* b22  = (const float*)d_in[6];
    const float* W31  = (const float*)d_in[7];
    const float* b31  = (const float*)d_in[8];
    const float* W32  = (const float*)d_in[9];
    const float* b32  = (const float*)d_in[10];
    const float* Amat = (const float*)d_in[11];
    const float* Gmat = (const float*)d_in[12];
    const float* mean = (const float*)d_in[13];
    const float* std_ = (const float*)d_in[14];

    const int B = in_sizes[0] / NN;
    const int block = 256;
    const int grid = (B + block - 1) / block;

    barrier_policy_kernel<<<grid, block, 0, stream>>>(
        x, W1, b1, W21, b21, W22, b22, W31, b31, W32, b32,
        Amat, Gmat, mean, std_, (float*)d_out, B);
}

// Round 4
// 73.230 us; speedup vs baseline: 2.1126x; 2.1126x over previous
//
#include <hip/hip_runtime.h>

#define NN 8
#define MM 8
#define NH1 64
#define NH2 32

#define FOR8(OP) OP(0) OP(1) OP(2) OP(3) OP(4) OP(5) OP(6) OP(7)

__global__ __launch_bounds__(256, 2) void barrier_policy_kernel(
    const float* __restrict__ x_g,
    const float* __restrict__ W1,  const float* __restrict__ b1,
    const float* __restrict__ W21, const float* __restrict__ b21,
    const float* __restrict__ W22, const float* __restrict__ b22,
    const float* __restrict__ W31, const float* __restrict__ b31,
    const float* __restrict__ W32, const float* __restrict__ b32,
    const float* __restrict__ Amat, const float* __restrict__ Gmat,
    const float* __restrict__ mean, const float* __restrict__ std_,
    float* __restrict__ out, int B)
{
    const int row = blockIdx.x * blockDim.x + threadIdx.x;
    if (row >= B) return;

    // ---- load x (vectorized, 32B/thread) ----
    float x[NN];
    {
        const float4* xv = reinterpret_cast<const float4*>(x_g + (size_t)row * NN);
        float4 a0 = xv[0], a1 = xv[1];
        x[0] = a0.x; x[1] = a0.y; x[2] = a0.z; x[3] = a0.w;
        x[4] = a1.x; x[5] = a1.y; x[6] = a1.z; x[7] = a1.w;
    }

    // ---- un-normalized state ----
    float x0[NN];
#pragma unroll
    for (int i = 0; i < NN; ++i) x0[i] = fmaf(x[i], std_[i], mean[i]);

    // ---- layer 1 fused into layer 2 ----
    float x21[NH2], x22[NH2];
#pragma unroll
    for (int j = 0; j < NH2; ++j) { x21[j] = b21[j]; x22[j] = b22[j]; }
#pragma unroll
    for (int k = 0; k < NH1; ++k) {
        float acc = b1[k];
#pragma unroll
        for (int i = 0; i < NN; ++i) acc = fmaf(x[i], W1[i * NH1 + k], acc);
        const float h = fmaxf(acc, 0.0f);
#pragma unroll
        for (int j = 0; j < NH2; ++j) {
            x21[j] = fmaf(h, W21[k * NH2 + j], x21[j]);
            x22[j] = fmaf(h, W22[k * NH2 + j], x22[j]);
        }
    }
#pragma unroll
    for (int j = 0; j < NH2; ++j) {
        x21[j] = fmaxf(x21[j], 0.0f);
        x22[j] = fmaxf(x22[j], 0.0f);
    }

    // ---- heads ----
    float p[MM];
#pragma unroll
    for (int j = 0; j < MM; ++j) {
        float acc = b31[j];
#pragma unroll
        for (int k = 0; k < NH2; ++k) acc = fmaf(x21[k], W31[k * MM + j], acc);
        p[j] = acc;
    }
    float s = b32[0];
#pragma unroll
    for (int k = 0; k < NH2; ++k) s = fmaf(x22[k], W32[k], s);
    const float alphax = 4.0f / (1.0f + __expf(-s));

    // ---- barrier terms ----
    float hx = 16.0f;
#pragma unroll
    for (int i = 0; i < NN; ++i) hx = fmaf(-x0[i], x0[i], hx);

    float dh[NN];
#pragma unroll
    for (int i = 0; i < NN; ++i) dh[i] = -2.0f * x0[i];

    float Lfhx = 0.0f;
#pragma unroll
    for (int i = 0; i < NN; ++i) {
        float fx = 0.0f;
#pragma unroll
        for (int k = 0; k < NN; ++k) fx = fmaf(Amat[i * NN + k], x0[k], fx);
        Lfhx = fmaf(dh[i], fx, Lfhx);
    }

    float g[MM];
#pragma unroll
    for (int j = 0; j < MM; ++j) {
        float acc = 0.0f;
#pragma unroll
        for (int i = 0; i < NN; ++i) acc = fmaf(dh[i], Gmat[i * MM + j], acc);
        g[j] = acc;
    }

    const float c0 = fmaf(alphax, hx, Lfhx);

    // =====================================================================
    // QP via exact piecewise-linear root isolation — FULLY SCALARIZED.
    // No arrays below this line: every value is a named register so nothing
    // can be demoted to scratch (round-3 post-mortem: array demotion caused
    // 470 MB/dispatch of spill traffic).
    // =====================================================================
#define DECL_PG(j) const float p##j = p[j]; const float g##j = g[j];
    FOR8(DECL_PG)
#undef DECL_PG

    // c(lam) = c0 + sum_j g_j clip(-p_j + lam g_j, -1, 1): nondecreasing,
    // piecewise-linear, breakpoints (p_j -/+ 1)/g_j.
    auto c_of = [&](float lam) -> float {
        float c = c0;
#define CTERM(j) { float u = fmaf(lam, g##j, -p##j);                  \
                   u = fminf(fmaxf(u, -1.0f), 1.0f);                  \
                   c = fmaf(g##j, u, c); }
        FOR8(CTERM)
#undef CTERM
        return c;
    };

    const bool viol = (c_of(0.0f) < 0.0f);

    const float BIGR = 3.0e38f;         // sentinel: no right bracket found
    float lamL = 0.0f, lamR = BIGR;
    // 16 independent c evaluations (branchless; g==0 gives inf/NaN bp which
    // the >0 / <lamR comparisons safely reject).
#define BP(j) {                                                        \
        const float bpa = (p##j - 1.0f) / g##j;                        \
        const float bpb = (p##j + 1.0f) / g##j;                        \
        const float ca = c_of(bpa);                                    \
        const float cb = c_of(bpb);                                    \
        lamL = (bpa > 0.0f && ca <  0.0f && bpa > lamL) ? bpa : lamL;  \
        lamR = (bpa > 0.0f && ca >= 0.0f && bpa < lamR) ? bpa : lamR;  \
        lamL = (bpb > 0.0f && cb <  0.0f && bpb > lamL) ? bpb : lamL;  \
        lamR = (bpb > 0.0f && cb >= 0.0f && bpb < lamR) ? bpb : lamR;  \
    }
    FOR8(BP)
#undef BP

    // lam_t strictly inside the root's linear segment (same segment the
    // reference's 60-step bisection lands in). Infeasible => classify at the
    // reference's capped bracket 2^40. !viol => lam = 0.
    const bool infeas = (lamR == BIGR);
    float lam_t = infeas ? 1.099511627776e12f : 0.5f * (lamL + lamR);
    lam_t = viol ? lam_t : 0.0f;

    // frozen active set -> closed-form lambda (exact KKT refinement, == ref)
    float denom = 0.0f, num = c0;
#define ASET(j)                                                        \
    const float ur##j = fmaf(lam_t, g##j, -p##j);                      \
    const bool lo##j = (ur##j <= -1.0f);                               \
    const bool hi##j = (ur##j >=  1.0f);                               \
    denom += (!(lo##j || hi##j)) ? g##j * g##j : 0.0f;                 \
    num   += lo##j ? -g##j : (hi##j ? g##j : -g##j * p##j);
    FOR8(ASET)
#undef ASET

    const float lam = viol ? (-num / (denom + 1e-12f)) : 0.0f;

#define UOUT(j) const float uo##j =                                    \
    lo##j ? -1.0f : (hi##j ? 1.0f : fmaf(lam, g##j, -p##j));
    FOR8(UOUT)
#undef UOUT

    // ---- store (vectorized) ----
    float4* ov = reinterpret_cast<float4*>(out + (size_t)row * MM);
    ov[0] = make_float4(uo0, uo1, uo2, uo3);
    ov[1] = make_float4(uo4, uo5, uo6, uo7);
}

extern "C" void kernel_launch(void* const* d_in, const int* in_sizes, int n_in,
                              void* d_out, int out_size, void* d_ws, size_t ws_size,
                              hipStream_t stream) {
    const float* x    = (const float*)d_in[0];
    const float* W1   = (const float*)d_in[1];
    const float* b1   = (const float*)d_in[2];
    const float* W21  = (const float*)d_in[3];
    const float* b21  = (const float*)d_in[4];
    const float* W22  = (const float*)d_in[5];
    const float* b22  = (const float*)d_in[6];
    const float* W31  = (const float*)d_in[7];
    const float* b31  = (const float*)d_in[8];
    const float* W32  = (const float*)d_in[9];
    const float* b32  = (const float*)d_in[10];
    const float* Amat = (const float*)d_in[11];
    const float* Gmat = (const float*)d_in[12];
    const float* mean = (const float*)d_in[13];
    const float* std_ = (const float*)d_in[14];

    const int B = in_sizes[0] / NN;
    const int block = 256;
    const int grid = (B + block - 1) / block;

    barrier_policy_kernel<<<grid, block, 0, stream>>>(
        x, W1, b1, W21, b21, W22, b22, W31, b31, W32, b32,
        Amat, Gmat, mean, std_, (float*)d_out, B);
}

// Round 6
// 51.684 us; speedup vs baseline: 2.9932x; 1.4169x over previous
//
#include <hip/hip_runtime.h>

#define NN 8
#define MM 8
#define NH1 64
#define NH2 32

#define FOR8(OP) OP(0) OP(1) OP(2) OP(3) OP(4) OP(5) OP(6) OP(7)

typedef float v2f __attribute__((ext_vector_type(2)));

__global__ __launch_bounds__(256, 2) void barrier_policy_kernel(
    const float* __restrict__ x_g,
    const float* __restrict__ W1,  const float* __restrict__ b1,
    const float* __restrict__ W21, const float* __restrict__ b21,
    const float* __restrict__ W22, const float* __restrict__ b22,
    const float* __restrict__ W31, const float* __restrict__ b31,
    const float* __restrict__ W32, const float* __restrict__ b32,
    const float* __restrict__ Amat, const float* __restrict__ Gmat,
    const float* __restrict__ mean, const float* __restrict__ std_,
    float* __restrict__ out, int B)
{
    const int row = blockIdx.x * blockDim.x + threadIdx.x;
    if (row >= B) return;

    // ---- load x (vectorized, 32B/thread) ----
    float x[NN];
    {
        const float4* xv = reinterpret_cast<const float4*>(x_g + (size_t)row * NN);
        float4 a0 = xv[0], a1 = xv[1];
        x[0] = a0.x; x[1] = a0.y; x[2] = a0.z; x[3] = a0.w;
        x[4] = a1.x; x[5] = a1.y; x[6] = a1.z; x[7] = a1.w;
    }

    // ---- un-normalized state ----
    float x0[NN];
#pragma unroll
    for (int i = 0; i < NN; ++i) x0[i] = fmaf(x[i], std_[i], mean[i]);

    // =====================================================================
    // MLP in packed FP32 (v_pk_fma_f32). Pairings preserve the scalar
    // accumulation order exactly:
    //  - layer1: pack the TWO OUTPUT channels (2k2, 2k2+1); serial over i
    //  - layer2: pack output pairs j; serial over k (h[2k2] then h[2k2+1])
    //  - p-head: pack output pairs j; serial over k
    // =====================================================================
    const v2f* b21v = (const v2f*)b21;
    const v2f* b22v = (const v2f*)b22;
    v2f a21[NH2 / 2], a22[NH2 / 2];
#pragma unroll
    for (int j2 = 0; j2 < NH2 / 2; ++j2) { a21[j2] = b21v[j2]; a22[j2] = b22v[j2]; }

#pragma unroll
    for (int k2 = 0; k2 < NH1 / 2; ++k2) {
        // layer-1 pair: h[2k2], h[2k2+1]
        v2f acc = ((const v2f*)b1)[k2];
#pragma unroll
        for (int i = 0; i < NN; ++i) {
            const v2f w = *(const v2f*)(W1 + i * NH1 + 2 * k2);
            const v2f xi = { x[i], x[i] };
            acc = __builtin_elementwise_fma(xi, w, acc);
        }
        const v2f zero2 = { 0.0f, 0.0f };
        const v2f h2 = __builtin_elementwise_max(acc, zero2);

        // layer-2 accumulate: first h[2k2] (row 2k2), then h[2k2+1] (row 2k2+1)
        const v2f ha = h2.xx, hb = h2.yy;
        const v2f* w21a = (const v2f*)(W21 + (2 * k2) * NH2);
        const v2f* w21b = (const v2f*)(W21 + (2 * k2 + 1) * NH2);
        const v2f* w22a = (const v2f*)(W22 + (2 * k2) * NH2);
        const v2f* w22b = (const v2f*)(W22 + (2 * k2 + 1) * NH2);
#pragma unroll
        for (int j2 = 0; j2 < NH2 / 2; ++j2) {
            a21[j2] = __builtin_elementwise_fma(ha, w21a[j2], a21[j2]);
            a22[j2] = __builtin_elementwise_fma(ha, w22a[j2], a22[j2]);
        }
#pragma unroll
        for (int j2 = 0; j2 < NH2 / 2; ++j2) {
            a21[j2] = __builtin_elementwise_fma(hb, w21b[j2], a21[j2]);
            a22[j2] = __builtin_elementwise_fma(hb, w22b[j2], a22[j2]);
        }
    }
    {
        const v2f zero2 = { 0.0f, 0.0f };
#pragma unroll
        for (int j2 = 0; j2 < NH2 / 2; ++j2) {
            a21[j2] = __builtin_elementwise_max(a21[j2], zero2);
            a22[j2] = __builtin_elementwise_max(a22[j2], zero2);
        }
    }

    // ---- p-head: pack output pairs (4 v2f), serial over k ----
    v2f pv[MM / 2];
#pragma unroll
    for (int j2 = 0; j2 < MM / 2; ++j2) pv[j2] = ((const v2f*)b31)[j2];
#pragma unroll
    for (int k2 = 0; k2 < NH2 / 2; ++k2) {
        const v2f hka = a21[k2].xx, hkb = a21[k2].yy;
        const v2f* w31a = (const v2f*)(W31 + (2 * k2) * MM);
        const v2f* w31b = (const v2f*)(W31 + (2 * k2 + 1) * MM);
#pragma unroll
        for (int j2 = 0; j2 < MM / 2; ++j2)
            pv[j2] = __builtin_elementwise_fma(hka, w31a[j2], pv[j2]);
#pragma unroll
        for (int j2 = 0; j2 < MM / 2; ++j2)
            pv[j2] = __builtin_elementwise_fma(hkb, w31b[j2], pv[j2]);
    }

    // ---- alpha-head: scalar (preserves exact serial rounding) ----
    float s = b32[0];
#pragma unroll
    for (int k2 = 0; k2 < NH2 / 2; ++k2) {
        s = fmaf(a22[k2].x, W32[2 * k2], s);
        s = fmaf(a22[k2].y, W32[2 * k2 + 1], s);
    }
    const float alphax = 4.0f / (1.0f + __expf(-s));

    // ---- barrier terms (scalar, small) ----
    float hx = 16.0f;
#pragma unroll
    for (int i = 0; i < NN; ++i) hx = fmaf(-x0[i], x0[i], hx);

    float dh[NN];
#pragma unroll
    for (int i = 0; i < NN; ++i) dh[i] = -2.0f * x0[i];

    float Lfhx = 0.0f;
#pragma unroll
    for (int i = 0; i < NN; ++i) {
        float fx = 0.0f;
#pragma unroll
        for (int k = 0; k < NN; ++k) fx = fmaf(Amat[i * NN + k], x0[k], fx);
        Lfhx = fmaf(dh[i], fx, Lfhx);
    }

    float g[MM];
#pragma unroll
    for (int j = 0; j < MM; ++j) {
        float acc = 0.0f;
#pragma unroll
        for (int i = 0; i < NN; ++i) acc = fmaf(dh[i], Gmat[i * MM + j], acc);
        g[j] = acc;
    }

    const float c0 = fmaf(alphax, hx, Lfhx);

    // =====================================================================
    // QP via exact piecewise-linear root isolation — fully scalarized
    // (no arrays -> nothing can demote to scratch; round-3 lesson).
    // Breakpoints via v_rcp (approx only SELECTS the segment; the KKT
    // refinement below is exact, so output error ~ machine eps).
    // =====================================================================
#define DECL_PG(j) const float p##j = (j & 1) ? pv[j >> 1].y : pv[j >> 1].x; \
                   const float g##j = g[j];
    FOR8(DECL_PG)
#undef DECL_PG

    auto c_of = [&](float lam) -> float {
        float c = c0;
#define CTERM(j) { float u = fmaf(lam, g##j, -p##j);                  \
                   u = fminf(fmaxf(u, -1.0f), 1.0f);                  \
                   c = fmaf(g##j, u, c); }
        FOR8(CTERM)
#undef CTERM
        return c;
    };

    const bool viol = (c_of(0.0f) < 0.0f);

    const float BIGR = 3.0e38f;         // sentinel: no right bracket found
    float lamL = 0.0f, lamR = BIGR;
#define BP(j) {                                                        \
        const float rg = __builtin_amdgcn_rcpf(g##j);                  \
        const float bpa = (p##j - 1.0f) * rg;                          \
        const float bpb = (p##j + 1.0f) * rg;                          \
        const float ca = c_of(bpa);                                    \
        const float cb = c_of(bpb);                                    \
        lamL = (bpa > 0.0f && ca <  0.0f && bpa > lamL) ? bpa : lamL;  \
        lamR = (bpa > 0.0f && ca >= 0.0f && bpa < lamR) ? bpa : lamR;  \
        lamL = (bpb > 0.0f && cb <  0.0f && bpb > lamL) ? bpb : lamL;  \
        lamR = (bpb > 0.0f && cb >= 0.0f && bpb < lamR) ? bpb : lamR;  \
    }
    FOR8(BP)
#undef BP

    // lam_t strictly inside the root's linear segment (same segment the
    // reference's 60-step bisection lands in). Infeasible => classify at the
    // reference's capped bracket 2^40. !viol => lam = 0.
    const bool infeas = (lamR == BIGR);
    float lam_t = infeas ? 1.099511627776e12f : 0.5f * (lamL + lamR);
    lam_t = viol ? lam_t : 0.0f;

    // frozen active set -> closed-form lambda (exact KKT refinement, == ref)
    float denom = 0.0f, num = c0;
#define ASET(j)                                                        \
    const float ur##j = fmaf(lam_t, g##j, -p##j);                      \
    const bool lo##j = (ur##j <= -1.0f);                               \
    const bool hi##j = (ur##j >=  1.0f);                               \
    denom += (!(lo##j || hi##j)) ? g##j * g##j : 0.0f;                 \
    num   += lo##j ? -g##j : (hi##j ? g##j : -g##j * p##j);
    FOR8(ASET)
#undef ASET

    const float lam = viol ? (-num / (denom + 1e-12f)) : 0.0f;

#define UOUT(j) const float uo##j =                                    \
    lo##j ? -1.0f : (hi##j ? 1.0f : fmaf(lam, g##j, -p##j));
    FOR8(UOUT)
#undef UOUT

    // ---- store (vectorized) ----
    float4* ov = reinterpret_cast<float4*>(out + (size_t)row * MM);
    ov[0] = make_float4(uo0, uo1, uo2, uo3);
    ov[1] = make_float4(uo4, uo5, uo6, uo7);
}

extern "C" void kernel_launch(void* const* d_in, const int* in_sizes, int n_in,
                              void* d_out, int out_size, void* d_ws, size_t ws_size,
                              hipStream_t stream) {
    const float* x    = (const float*)d_in[0];
    const float* W1   = (const float*)d_in[1];
    const float* b1   = (const float*)d_in[2];
    const float* W21  = (const float*)d_in[3];
    const float* b21  = (const float*)d_in[4];
    const float* W22  = (const float*)d_in[5];
    const float* b22  = (const float*)d_in[6];
    const float* W31  = (const float*)d_in[7];
    const float* b31  = (const float*)d_in[8];
    const float* W32  = (const float*)d_in[9];
    const float* b32  = (const float*)d_in[10];
    const float* Amat = (const float*)d_in[11];
    const float* Gmat = (const float*)d_in[12];
    const float* mean = (const float*)d_in[13];
    const float* std_ = (const float*)d_in[14];

    const int B = in_sizes[0] / NN;
    const int block = 256;
    const int grid = (B + block - 1) / block;

    barrier_policy_kernel<<<grid, block, 0, stream>>>(
        x, W1, b1, W21, b21, W22, b22, W31, b31, W32, b32,
        Amat, Gmat, mean, std_, (float*)d_out, B);
}